// Round 1
// baseline (726.183 us; speedup 1.0000x reference)
//
#include <hip/hip_runtime.h>
#include <hip/hip_bf16.h>

// GraphSAGE 3-layer forward on MI355X.
// Strategy: transform-then-aggregate (linear ops commute with mean), CSR built
// per call (no float atomics), wave-per-node aggregation, fused log_softmax.

#define WAVE 64

// ---------------- CSR build ----------------

__global__ void hist_kernel(const int* __restrict__ dst, int* __restrict__ deg, int E) {
    int e = blockIdx.x * blockDim.x + threadIdx.x;
    if (e < E) atomicAdd(&deg[dst[e]], 1);
}

__global__ __launch_bounds__(1024) void scan_kernel(const int* __restrict__ deg,
                                                    int* __restrict__ row_ptr,
                                                    int* __restrict__ cursor, int N) {
    __shared__ int sh[1024];
    int t = threadIdx.x;
    int chunk = (N + 1023) >> 10;
    int beg = t * chunk;
    int end = beg + chunk; if (end > N) end = N;
    int s = 0;
    for (int i = beg; i < end && i < N; ++i) s += deg[i];
    sh[t] = s;
    __syncthreads();
    for (int off = 1; off < 1024; off <<= 1) {
        int v = (t >= off) ? sh[t - off] : 0;
        __syncthreads();
        sh[t] += v;
        __syncthreads();
    }
    int run = sh[t] - s;  // exclusive prefix of this thread's chunk
    for (int i = beg; i < end && i < N; ++i) {
        row_ptr[i] = run;
        cursor[i] = run;
        run += deg[i];
    }
    if (t == 1023) row_ptr[N] = sh[1023];
}

__global__ void fill_kernel(const int* __restrict__ dst, const int* __restrict__ srcv,
                            int* __restrict__ cursor, int* __restrict__ adj, int E) {
    int e = blockIdx.x * blockDim.x + threadIdx.x;
    if (e < E) {
        int p = atomicAdd(&cursor[dst[e]], 1);
        adj[p] = srcv[e];
    }
}

// ---------------- GEMM: C[n, 0:Dout) = H.Wl rows, C[n, Dout:2*Dout) = H.Wr ----------------
// H: N x 128 row-major. Wl/Wr: Dout x 128 row-major. C: N x ldC (ldC = 2*Dout).
// 64x64 tile, 256 threads, 4x4 micro-tile, K=128 fully staged.

__global__ __launch_bounds__(256) void gemm_kernel(const float* __restrict__ H,
                                                   const float* __restrict__ Wl,
                                                   const float* __restrict__ Wr,
                                                   float* __restrict__ C,
                                                   int N, int Dout, int ldC) {
    __shared__ float As[64][129];  // +1 pad: compute reads hit distinct banks
    __shared__ float Bs[64][129];

    int tid = threadIdx.x;
    int tx = tid & 15, ty = tid >> 4;
    int n0 = blockIdx.x * 64;
    int col0 = blockIdx.y * 64;
    const float* Wbase = (col0 < Dout) ? (Wl + (size_t)col0 * 128)
                                       : (Wr + (size_t)(col0 - Dout) * 128);
    const float4* H4 = (const float4*)H;
    const float4* W4 = (const float4*)Wbase;

    // Stage A (64 rows x 128 k) and B (64 w-rows x 128 k).
#pragma unroll
    for (int i = 0; i < 8; ++i) {
        int f = tid + i * 256;         // float4 index, 0..2047
        int r = f >> 5, k4 = f & 31;
        int gr = n0 + r; if (gr > N - 1) gr = N - 1;
        float4 a = H4[(size_t)gr * 32 + k4];
        As[r][k4 * 4 + 0] = a.x; As[r][k4 * 4 + 1] = a.y;
        As[r][k4 * 4 + 2] = a.z; As[r][k4 * 4 + 3] = a.w;
        float4 b = W4[(size_t)r * 32 + k4];
        Bs[r][k4 * 4 + 0] = b.x; Bs[r][k4 * 4 + 1] = b.y;
        Bs[r][k4 * 4 + 2] = b.z; Bs[r][k4 * 4 + 3] = b.w;
    }
    __syncthreads();

    float acc[4][4] = {};
#pragma unroll 8
    for (int k = 0; k < 128; ++k) {
        float a0 = As[ty * 4 + 0][k], a1 = As[ty * 4 + 1][k];
        float a2 = As[ty * 4 + 2][k], a3 = As[ty * 4 + 3][k];
        float b0 = Bs[tx * 4 + 0][k], b1 = Bs[tx * 4 + 1][k];
        float b2 = Bs[tx * 4 + 2][k], b3 = Bs[tx * 4 + 3][k];
        acc[0][0] += a0 * b0; acc[0][1] += a0 * b1; acc[0][2] += a0 * b2; acc[0][3] += a0 * b3;
        acc[1][0] += a1 * b0; acc[1][1] += a1 * b1; acc[1][2] += a1 * b2; acc[1][3] += a1 * b3;
        acc[2][0] += a2 * b0; acc[2][1] += a2 * b1; acc[2][2] += a2 * b2; acc[2][3] += a2 * b3;
        acc[3][0] += a3 * b0; acc[3][1] += a3 * b1; acc[3][2] += a3 * b2; acc[3][3] += a3 * b3;
    }

#pragma unroll
    for (int i = 0; i < 4; ++i) {
        int n = n0 + ty * 4 + i;
        if (n < N) {
            float* cp = C + (size_t)n * ldC + col0 + tx * 4;
            cp[0] = acc[i][0]; cp[1] = acc[i][1]; cp[2] = acc[i][2]; cp[3] = acc[i][3];
        }
    }
}

// ---------------- Aggregation (layers 0,1): wave per node, 128 dims as float2 ----------------
// C: N x 256 (cols 0..127 = Wl-transformed, 128..255 = Wr-transformed self path)

__global__ __launch_bounds__(256) void agg_relu_kernel(const float* __restrict__ C,
                                                       const int* __restrict__ row_ptr,
                                                       const int* __restrict__ adj,
                                                       const float* __restrict__ bias,
                                                       float* __restrict__ hout, int N) {
    int node = (int)((blockIdx.x * blockDim.x + threadIdx.x) >> 6);
    int lane = threadIdx.x & 63;
    if (node >= N) return;
    int beg = row_ptr[node], end = row_ptr[node + 1];
    float sx = 0.f, sy = 0.f;
    for (int e = beg; e < end; ++e) {
        int s = adj[e];
        float2 v = ((const float2*)(C + (size_t)s * 256))[lane];
        sx += v.x; sy += v.y;
    }
    int deg = end - beg;
    float inv = 1.0f / (float)(deg > 1 ? deg : 1);
    float2 bb = ((const float2*)bias)[lane];
    float2 rr = ((const float2*)(C + (size_t)node * 256 + 128))[lane];
    float2 o;
    o.x = fmaxf(sx * inv + bb.x + rr.x, 0.f);
    o.y = fmaxf(sy * inv + bb.y + rr.y, 0.f);
    ((float2*)(hout + (size_t)node * 128))[lane] = o;
}

// ---------------- Final layer: aggregate 64 dims + fused log_softmax ----------------
// C: N x 128 (cols 0..63 = Wl path, 64..127 = Wr self path)

__global__ __launch_bounds__(256) void final_kernel(const float* __restrict__ C,
                                                    const int* __restrict__ row_ptr,
                                                    const int* __restrict__ adj,
                                                    const float* __restrict__ bias,
                                                    float* __restrict__ out, int N) {
    int node = (int)((blockIdx.x * blockDim.x + threadIdx.x) >> 6);
    int lane = threadIdx.x & 63;
    if (node >= N) return;
    int beg = row_ptr[node], end = row_ptr[node + 1];
    float sum = 0.f;
    for (int e = beg; e < end; ++e) {
        int s = adj[e];
        sum += C[(size_t)s * 128 + lane];
    }
    int deg = end - beg;
    float inv = 1.0f / (float)(deg > 1 ? deg : 1);
    float u = sum * inv + bias[lane] + C[(size_t)node * 128 + 64 + lane];

    // log_softmax over the 64 lanes of this wave
    float m = u;
#pragma unroll
    for (int off = 32; off > 0; off >>= 1) m = fmaxf(m, __shfl_xor(m, off));
    float ex = __expf(u - m);
    float se = ex;
#pragma unroll
    for (int off = 32; off > 0; off >>= 1) se += __shfl_xor(se, off);
    out[(size_t)node * 64 + lane] = (u - m) - __logf(se);
}

// ---------------- Launch ----------------

extern "C" void kernel_launch(void* const* d_in, const int* in_sizes, int n_in,
                              void* d_out, int out_size, void* d_ws, size_t ws_size,
                              hipStream_t stream) {
    const float* x   = (const float*)d_in[0];
    const int*   ei  = (const int*)d_in[1];
    const float* Wl0 = (const float*)d_in[2];
    const float* bl0 = (const float*)d_in[3];
    const float* Wr0 = (const float*)d_in[4];
    const float* Wl1 = (const float*)d_in[5];
    const float* bl1 = (const float*)d_in[6];
    const float* Wr1 = (const float*)d_in[7];
    const float* Wl2 = (const float*)d_in[8];
    const float* bl2 = (const float*)d_in[9];
    const float* Wr2 = (const float*)d_in[10];
    float* out = (float*)d_out;

    const int N = in_sizes[0] / 128;   // 50000
    const int E = in_sizes[1] / 2;     // 800000

    char* ws = (char*)d_ws;
    auto alloc = [&](size_t bytes) {
        char* p = ws;
        ws += (bytes + 255) & ~(size_t)255;
        return p;
    };
    int*   deg     = (int*)alloc((size_t)N * 4);
    int*   row_ptr = (int*)alloc((size_t)(N + 1) * 4);
    int*   cursor  = (int*)alloc((size_t)N * 4);
    int*   adj     = (int*)alloc((size_t)E * 4);
    float* C       = (float*)alloc((size_t)N * 256 * 4);  // transformed features
    float* hA      = (float*)alloc((size_t)N * 128 * 4);
    float* hB      = (float*)alloc((size_t)N * 128 * 4);

    const int* dstp = ei;       // edge_index row 0 = dst
    const int* srcp = ei + E;   // edge_index row 1 = src

    // CSR build (per call; workspace is re-poisoned each launch)
    hipMemsetAsync(deg, 0, (size_t)N * 4, stream);
    hist_kernel<<<(E + 255) / 256, 256, 0, stream>>>(dstp, deg, E);
    scan_kernel<<<1, 1024, 0, stream>>>(deg, row_ptr, cursor, N);
    fill_kernel<<<(E + 255) / 256, 256, 0, stream>>>(dstp, srcp, cursor, adj, E);

    dim3 blk(256);
    dim3 g01((N + 63) / 64, 4);   // 256 output cols
    dim3 g2((N + 63) / 64, 2);    // 128 output cols
    int aggBlocks = (N * 64 + 255) / 256;  // one wave per node, 4 waves/block

    // Layer 0
    gemm_kernel<<<g01, blk, 0, stream>>>(x, Wl0, Wr0, C, N, 128, 256);
    agg_relu_kernel<<<aggBlocks, blk, 0, stream>>>(C, row_ptr, adj, bl0, hA, N);
    // Layer 1
    gemm_kernel<<<g01, blk, 0, stream>>>(hA, Wl1, Wr1, C, N, 128, 256);
    agg_relu_kernel<<<aggBlocks, blk, 0, stream>>>(C, row_ptr, adj, bl1, hB, N);
    // Layer 2 + log_softmax
    gemm_kernel<<<g2, blk, 0, stream>>>(hB, Wl2, Wr2, C, N, 64, 128);
    final_kernel<<<aggBlocks, blk, 0, stream>>>(C, row_ptr, adj, bl2, out, N);
}

// Round 2
// 489.977 us; speedup vs baseline: 1.4821x; 1.4821x over previous
//
#include <hip/hip_runtime.h>
#include <hip/hip_bf16.h>

// GraphSAGE 3-layer forward, MI355X. Round 2:
//  - multi-block scan (was 111us single-block)
//  - bf16 MFMA GEMM (16x16x32), no LDS: A/B fragments loaded direct from global
//  - bf16 feature matrices end-to-end (halves gather traffic); fp32 accum everywhere

typedef __attribute__((ext_vector_type(8))) short bf16x8;
typedef __attribute__((ext_vector_type(4))) float f32x4;

__device__ __forceinline__ unsigned short f2bf(float f) {
    unsigned int u = __builtin_bit_cast(unsigned int, f);
    u += 0x7fffu + ((u >> 16) & 1u);           // round-to-nearest-even
    return (unsigned short)(u >> 16);
}
__device__ __forceinline__ float bf2f(unsigned int bits16) {
    return __builtin_bit_cast(float, bits16 << 16);
}

// ---------------- CSR build ----------------

__global__ void hist_kernel(const int* __restrict__ dst, int* __restrict__ deg, int E) {
    int e = blockIdx.x * blockDim.x + threadIdx.x;
    if (e < E) atomicAdd(&deg[dst[e]], 1);
}

__global__ __launch_bounds__(256) void partial_kernel(const int* __restrict__ deg,
                                                      int* __restrict__ blockSums, int N) {
    __shared__ int sh[256];
    int t = threadIdx.x;
    int i = blockIdx.x * 256 + t;
    int v = (i < N) ? deg[i] : 0;
    sh[t] = v; __syncthreads();
    for (int off = 128; off > 0; off >>= 1) {
        if (t < off) sh[t] += sh[t + off];
        __syncthreads();
    }
    if (t == 0) blockSums[blockIdx.x] = sh[0];
}

__global__ __launch_bounds__(256) void offsets_kernel(const int* __restrict__ blockSums,
                                                      int* __restrict__ blockOff, int G,
                                                      int* __restrict__ rowptr_last) {
    __shared__ int sh[256];
    int t = threadIdx.x;
    int v = (t < G) ? blockSums[t] : 0;
    sh[t] = v; __syncthreads();
    for (int off = 1; off < 256; off <<= 1) {
        int u = (t >= off) ? sh[t - off] : 0;
        __syncthreads();
        sh[t] += u;
        __syncthreads();
    }
    if (t < G) blockOff[t] = sh[t] - v;     // exclusive
    if (t == 255) *rowptr_last = sh[255];   // total == E
}

__global__ __launch_bounds__(256) void scatter_kernel(const int* __restrict__ deg,
                                                      const int* __restrict__ blockOff,
                                                      int* __restrict__ row_ptr,
                                                      int* __restrict__ cursor, int N) {
    __shared__ int sh[256];
    int t = threadIdx.x;
    int i = blockIdx.x * 256 + t;
    int v = (i < N) ? deg[i] : 0;
    sh[t] = v; __syncthreads();
    for (int off = 1; off < 256; off <<= 1) {
        int u = (t >= off) ? sh[t - off] : 0;
        __syncthreads();
        sh[t] += u;
        __syncthreads();
    }
    if (i < N) {
        int excl = blockOff[blockIdx.x] + sh[t] - v;
        row_ptr[i] = excl;
        cursor[i] = excl;
    }
}

__global__ void fill_kernel(const int* __restrict__ dst, const int* __restrict__ srcv,
                            int* __restrict__ cursor, int* __restrict__ adj, int E) {
    int e = blockIdx.x * blockDim.x + threadIdx.x;
    if (e < E) {
        int p = atomicAdd(&cursor[dst[e]], 1);
        adj[p] = srcv[e];
    }
}

// ---------------- casts ----------------

__global__ void cast_x_kernel(const float* __restrict__ in, unsigned short* __restrict__ out,
                              int npairs) {
    int i = blockIdx.x * blockDim.x + threadIdx.x;
    if (i < npairs) {
        float2 v = ((const float2*)in)[i];
        unsigned int p = (unsigned int)f2bf(v.x) | ((unsigned int)f2bf(v.y) << 16);
        ((unsigned int*)out)[i] = p;
    }
}

// all 6 weight tensors -> one contiguous bf16 region (offsets in elements)
__global__ void cast_w_kernel(const float* p0, const float* p1, const float* p2,
                              const float* p3, const float* p4, const float* p5,
                              unsigned short* __restrict__ out) {
    const float* ps[6] = {p0, p1, p2, p3, p4, p5};
    const int sizes[6] = {16384, 16384, 16384, 16384, 8192, 8192};
    const int offs[6]  = {0, 16384, 32768, 49152, 65536, 73728};
    int y = blockIdx.y;
    int i = blockIdx.x * 256 + threadIdx.x;         // pair index
    if (i * 2 < sizes[y]) {
        float2 v = ((const float2*)ps[y])[i];
        unsigned int p = (unsigned int)f2bf(v.x) | ((unsigned int)f2bf(v.y) << 16);
        ((unsigned int*)(out + offs[y]))[i] = p;
    }
}

// ---------------- MFMA GEMM ----------------
// C[n, col] = sum_k H[n,k] * W[col,k].  H: N x 128 bf16.  W tensors: Dout x 128 bf16.
// Block: 256 thr = 4 waves; tile 128 rows x 64 cols; wave = 32 rows.
// grid.y selects 64-col slab: y < half -> Wl rows y*64.., else Wr rows (y-half)*64..
// No LDS: A frag = 16B contiguous-K from H row; B frag = 16B contiguous-K from W row.

__global__ __launch_bounds__(256) void gemm_mfma_kernel(const unsigned short* __restrict__ H,
                                                        const unsigned short* __restrict__ Wl,
                                                        const unsigned short* __restrict__ Wr,
                                                        unsigned short* __restrict__ C,
                                                        int N, int ldC) {
    int wave = threadIdx.x >> 6;
    int lane = threadIdx.x & 63;
    int l15 = lane & 15, quad = lane >> 4;
    int y = blockIdx.y, half = gridDim.y >> 1;
    const unsigned short* W = (y < half) ? Wl : Wr;
    int wrow0 = (y < half ? y : y - half) * 64;
    int col0 = y * 64;
    int m0 = blockIdx.x * 128 + wave * 32;

    int r0 = m0 + l15;      if (r0 > N - 1) r0 = N - 1;
    int r1 = m0 + 16 + l15; if (r1 > N - 1) r1 = N - 1;
    const bf16x8* A0 = (const bf16x8*)(H + (size_t)r0 * 128);
    const bf16x8* A1 = (const bf16x8*)(H + (size_t)r1 * 128);

    f32x4 acc[2][4] = {};
#pragma unroll
    for (int ks = 0; ks < 4; ++ks) {               // k0 = ks*32
        int vidx = ks * 4 + quad;                  // 16B chunk index within 128-k row
        bf16x8 a0 = A0[vidx];
        bf16x8 a1 = A1[vidx];
#pragma unroll
        for (int j = 0; j < 4; ++j) {
            const bf16x8* B = (const bf16x8*)(W + (size_t)(wrow0 + j * 16 + l15) * 128);
            bf16x8 b = B[vidx];
            acc[0][j] = __builtin_amdgcn_mfma_f32_16x16x32_bf16(a0, b, acc[0][j], 0, 0, 0);
            acc[1][j] = __builtin_amdgcn_mfma_f32_16x16x32_bf16(a1, b, acc[1][j], 0, 0, 0);
        }
    }

#pragma unroll
    for (int i = 0; i < 2; ++i)
#pragma unroll
        for (int j = 0; j < 4; ++j)
#pragma unroll
            for (int r = 0; r < 4; ++r) {
                int row = m0 + i * 16 + quad * 4 + r;
                if (row < N) {
                    int col = col0 + j * 16 + l15;
                    C[(size_t)row * ldC + col] = f2bf(acc[i][j][r]);
                }
            }
}

// ---------------- Aggregation (layers 0,1): wave/node, bf16 C (N x 256) ----------------
// cols 0..127 = Wl path (aggregate), 128..255 = Wr self path. lane handles dims 2l,2l+1.

__global__ __launch_bounds__(256) void agg_relu_kernel(const unsigned short* __restrict__ C,
                                                       const int* __restrict__ row_ptr,
                                                       const int* __restrict__ adj,
                                                       const float* __restrict__ bias,
                                                       unsigned short* __restrict__ hout, int N) {
    int node = (int)((blockIdx.x * blockDim.x + threadIdx.x) >> 6);
    int lane = threadIdx.x & 63;
    if (node >= N) return;
    int beg = row_ptr[node], end = row_ptr[node + 1];
    float sx = 0.f, sy = 0.f;
    for (int e = beg; e < end; ++e) {
        int s = adj[e];
        unsigned int v = ((const unsigned int*)(C + (size_t)s * 256))[lane];
        sx += bf2f(v & 0xffffu);
        sy += bf2f(v >> 16);
    }
    int deg = end - beg;
    float inv = 1.0f / (float)(deg > 1 ? deg : 1);
    float2 bb = ((const float2*)bias)[lane];
    unsigned int rv = ((const unsigned int*)(C + (size_t)node * 256))[64 + lane];
    float ox = fmaxf(sx * inv + bb.x + bf2f(rv & 0xffffu), 0.f);
    float oy = fmaxf(sy * inv + bb.y + bf2f(rv >> 16), 0.f);
    unsigned int p = (unsigned int)f2bf(ox) | ((unsigned int)f2bf(oy) << 16);
    ((unsigned int*)(hout + (size_t)node * 128))[lane] = p;
}

// ---------------- Final layer: bf16 C (N x 128), fused log_softmax, fp32 out ----------------

__global__ __launch_bounds__(256) void final_kernel(const unsigned short* __restrict__ C,
                                                    const int* __restrict__ row_ptr,
                                                    const int* __restrict__ adj,
                                                    const float* __restrict__ bias,
                                                    float* __restrict__ out, int N) {
    int node = (int)((blockIdx.x * blockDim.x + threadIdx.x) >> 6);
    int lane = threadIdx.x & 63;
    if (node >= N) return;
    int beg = row_ptr[node], end = row_ptr[node + 1];
    float sum = 0.f;
    for (int e = beg; e < end; ++e) {
        int s = adj[e];
        sum += bf2f((unsigned int)C[(size_t)s * 128 + lane]);
    }
    int deg = end - beg;
    float inv = 1.0f / (float)(deg > 1 ? deg : 1);
    float u = sum * inv + bias[lane] + bf2f((unsigned int)C[(size_t)node * 128 + 64 + lane]);

    float m = u;
#pragma unroll
    for (int off = 32; off > 0; off >>= 1) m = fmaxf(m, __shfl_xor(m, off));
    float ex = __expf(u - m);
    float se = ex;
#pragma unroll
    for (int off = 32; off > 0; off >>= 1) se += __shfl_xor(se, off);
    out[(size_t)node * 64 + lane] = (u - m) - __logf(se);
}

// ---------------- Launch ----------------

extern "C" void kernel_launch(void* const* d_in, const int* in_sizes, int n_in,
                              void* d_out, int out_size, void* d_ws, size_t ws_size,
                              hipStream_t stream) {
    const float* x   = (const float*)d_in[0];
    const int*   ei  = (const int*)d_in[1];
    const float* Wl0 = (const float*)d_in[2];
    const float* bl0 = (const float*)d_in[3];
    const float* Wr0 = (const float*)d_in[4];
    const float* Wl1 = (const float*)d_in[5];
    const float* bl1 = (const float*)d_in[6];
    const float* Wr1 = (const float*)d_in[7];
    const float* Wl2 = (const float*)d_in[8];
    const float* bl2 = (const float*)d_in[9];
    const float* Wr2 = (const float*)d_in[10];
    float* out = (float*)d_out;

    const int N = in_sizes[0] / 128;   // 50000
    const int E = in_sizes[1] / 2;     // 800000
    const int G = (N + 255) / 256;     // scan blocks (196 <= 256)

    char* ws = (char*)d_ws;
    auto alloc = [&](size_t bytes) {
        char* p = ws;
        ws += (bytes + 255) & ~(size_t)255;
        return p;
    };
    int*   deg       = (int*)alloc((size_t)N * 4);
    int*   row_ptr   = (int*)alloc((size_t)(N + 1) * 4);
    int*   cursor    = (int*)alloc((size_t)N * 4);
    int*   adj       = (int*)alloc((size_t)E * 4);
    int*   blockSums = (int*)alloc((size_t)G * 4);
    int*   blockOff  = (int*)alloc((size_t)G * 4);
    unsigned short* xbf = (unsigned short*)alloc((size_t)N * 128 * 2);
    unsigned short* wbf = (unsigned short*)alloc((size_t)81920 * 2);
    unsigned short* C   = (unsigned short*)alloc((size_t)N * 256 * 2);
    unsigned short* hA  = (unsigned short*)alloc((size_t)N * 128 * 2);
    unsigned short* hB  = (unsigned short*)alloc((size_t)N * 128 * 2);

    const int* dstp = ei;       // edge_index row 0 = dst
    const int* srcp = ei + E;   // edge_index row 1 = src

    // CSR build
    hipMemsetAsync(deg, 0, (size_t)N * 4, stream);
    hist_kernel<<<(E + 255) / 256, 256, 0, stream>>>(dstp, deg, E);
    partial_kernel<<<G, 256, 0, stream>>>(deg, blockSums, N);
    offsets_kernel<<<1, 256, 0, stream>>>(blockSums, blockOff, G, row_ptr + N);
    scatter_kernel<<<G, 256, 0, stream>>>(deg, blockOff, row_ptr, cursor, N);
    fill_kernel<<<(E + 255) / 256, 256, 0, stream>>>(dstp, srcp, cursor, adj, E);

    // casts (x and 6 weight tensors)
    cast_x_kernel<<<(N * 64 + 255) / 256, 256, 0, stream>>>(x, xbf, N * 64);
    cast_w_kernel<<<dim3(32, 6), 256, 0, stream>>>(Wl0, Wr0, Wl1, Wr1, Wl2, Wr2, wbf);
    unsigned short* wl0 = wbf;
    unsigned short* wr0 = wbf + 16384;
    unsigned short* wl1 = wbf + 32768;
    unsigned short* wr1 = wbf + 49152;
    unsigned short* wl2 = wbf + 65536;
    unsigned short* wr2 = wbf + 73728;

    dim3 blk(256);
    int gemmRows = (N + 127) / 128;
    int aggBlocks = (N * 64 + 255) / 256;

    // Layer 0
    gemm_mfma_kernel<<<dim3(gemmRows, 4), blk, 0, stream>>>(xbf, wl0, wr0, C, N, 256);
    agg_relu_kernel<<<aggBlocks, blk, 0, stream>>>(C, row_ptr, adj, bl0, hA, N);
    // Layer 1
    gemm_mfma_kernel<<<dim3(gemmRows, 4), blk, 0, stream>>>(hA, wl1, wr1, C, N, 256);
    agg_relu_kernel<<<aggBlocks, blk, 0, stream>>>(C, row_ptr, adj, bl1, hB, N);
    // Layer 2 + log_softmax
    gemm_mfma_kernel<<<dim3(gemmRows, 2), blk, 0, stream>>>(hB, wl2, wr2, C, N, 128);
    final_kernel<<<aggBlocks, blk, 0, stream>>>(C, row_ptr, adj, bl2, out, N);
}

// Round 3
// 335.358 us; speedup vs baseline: 2.1654x; 1.4611x over previous
//
#include <hip/hip_runtime.h>
#include <hip/hip_bf16.h>

// GraphSAGE 3-layer forward, MI355X. Round 3:
//  - aggregation gathers batched: coalesced adj load + shfl-broadcast indices,
//    8 independent row-gathers in flight (was serial chain -> latency-bound)
//  - same MFMA GEMM / CSR / bf16 pipeline as R2

typedef __attribute__((ext_vector_type(8))) short bf16x8;
typedef __attribute__((ext_vector_type(4))) float f32x4;

__device__ __forceinline__ unsigned short f2bf(float f) {
    unsigned int u = __builtin_bit_cast(unsigned int, f);
    u += 0x7fffu + ((u >> 16) & 1u);           // round-to-nearest-even
    return (unsigned short)(u >> 16);
}
__device__ __forceinline__ float bf2f(unsigned int bits16) {
    return __builtin_bit_cast(float, bits16 << 16);
}

// ---------------- CSR build ----------------

__global__ void hist_kernel(const int* __restrict__ dst, int* __restrict__ deg, int E) {
    int e = blockIdx.x * blockDim.x + threadIdx.x;
    if (e < E) atomicAdd(&deg[dst[e]], 1);
}

__global__ __launch_bounds__(256) void partial_kernel(const int* __restrict__ deg,
                                                      int* __restrict__ blockSums, int N) {
    __shared__ int sh[256];
    int t = threadIdx.x;
    int i = blockIdx.x * 256 + t;
    int v = (i < N) ? deg[i] : 0;
    sh[t] = v; __syncthreads();
    for (int off = 128; off > 0; off >>= 1) {
        if (t < off) sh[t] += sh[t + off];
        __syncthreads();
    }
    if (t == 0) blockSums[blockIdx.x] = sh[0];
}

__global__ __launch_bounds__(256) void offsets_kernel(const int* __restrict__ blockSums,
                                                      int* __restrict__ blockOff, int G,
                                                      int* __restrict__ rowptr_last) {
    __shared__ int sh[256];
    int t = threadIdx.x;
    int v = (t < G) ? blockSums[t] : 0;
    sh[t] = v; __syncthreads();
    for (int off = 1; off < 256; off <<= 1) {
        int u = (t >= off) ? sh[t - off] : 0;
        __syncthreads();
        sh[t] += u;
        __syncthreads();
    }
    if (t < G) blockOff[t] = sh[t] - v;     // exclusive
    if (t == 255) *rowptr_last = sh[255];   // total == E
}

__global__ __launch_bounds__(256) void scatter_kernel(const int* __restrict__ deg,
                                                      const int* __restrict__ blockOff,
                                                      int* __restrict__ row_ptr,
                                                      int* __restrict__ cursor, int N) {
    __shared__ int sh[256];
    int t = threadIdx.x;
    int i = blockIdx.x * 256 + t;
    int v = (i < N) ? deg[i] : 0;
    sh[t] = v; __syncthreads();
    for (int off = 1; off < 256; off <<= 1) {
        int u = (t >= off) ? sh[t - off] : 0;
        __syncthreads();
        sh[t] += u;
        __syncthreads();
    }
    if (i < N) {
        int excl = blockOff[blockIdx.x] + sh[t] - v;
        row_ptr[i] = excl;
        cursor[i] = excl;
    }
}

__global__ void fill_kernel(const int* __restrict__ dst, const int* __restrict__ srcv,
                            int* __restrict__ cursor, int* __restrict__ adj, int E) {
    int e = blockIdx.x * blockDim.x + threadIdx.x;
    if (e < E) {
        int p = atomicAdd(&cursor[dst[e]], 1);
        adj[p] = srcv[e];
    }
}

// ---------------- casts ----------------

__global__ void cast_x_kernel(const float* __restrict__ in, unsigned short* __restrict__ out,
                              int npairs) {
    int i = blockIdx.x * blockDim.x + threadIdx.x;
    if (i < npairs) {
        float2 v = ((const float2*)in)[i];
        unsigned int p = (unsigned int)f2bf(v.x) | ((unsigned int)f2bf(v.y) << 16);
        ((unsigned int*)out)[i] = p;
    }
}

__global__ void cast_w_kernel(const float* p0, const float* p1, const float* p2,
                              const float* p3, const float* p4, const float* p5,
                              unsigned short* __restrict__ out) {
    const float* ps[6] = {p0, p1, p2, p3, p4, p5};
    const int sizes[6] = {16384, 16384, 16384, 16384, 8192, 8192};
    const int offs[6]  = {0, 16384, 32768, 49152, 65536, 73728};
    int y = blockIdx.y;
    int i = blockIdx.x * 256 + threadIdx.x;
    if (i * 2 < sizes[y]) {
        float2 v = ((const float2*)ps[y])[i];
        unsigned int p = (unsigned int)f2bf(v.x) | ((unsigned int)f2bf(v.y) << 16);
        ((unsigned int*)(out + offs[y]))[i] = p;
    }
}

// ---------------- MFMA GEMM (unchanged from R2) ----------------

__global__ __launch_bounds__(256) void gemm_mfma_kernel(const unsigned short* __restrict__ H,
                                                        const unsigned short* __restrict__ Wl,
                                                        const unsigned short* __restrict__ Wr,
                                                        unsigned short* __restrict__ C,
                                                        int N, int ldC) {
    int wave = threadIdx.x >> 6;
    int lane = threadIdx.x & 63;
    int l15 = lane & 15, quad = lane >> 4;
    int y = blockIdx.y, half = gridDim.y >> 1;
    const unsigned short* W = (y < half) ? Wl : Wr;
    int wrow0 = (y < half ? y : y - half) * 64;
    int col0 = y * 64;
    int m0 = blockIdx.x * 128 + wave * 32;

    int r0 = m0 + l15;      if (r0 > N - 1) r0 = N - 1;
    int r1 = m0 + 16 + l15; if (r1 > N - 1) r1 = N - 1;
    const bf16x8* A0 = (const bf16x8*)(H + (size_t)r0 * 128);
    const bf16x8* A1 = (const bf16x8*)(H + (size_t)r1 * 128);

    f32x4 acc[2][4] = {};
#pragma unroll
    for (int ks = 0; ks < 4; ++ks) {
        int vidx = ks * 4 + quad;
        bf16x8 a0 = A0[vidx];
        bf16x8 a1 = A1[vidx];
#pragma unroll
        for (int j = 0; j < 4; ++j) {
            const bf16x8* B = (const bf16x8*)(W + (size_t)(wrow0 + j * 16 + l15) * 128);
            bf16x8 b = B[vidx];
            acc[0][j] = __builtin_amdgcn_mfma_f32_16x16x32_bf16(a0, b, acc[0][j], 0, 0, 0);
            acc[1][j] = __builtin_amdgcn_mfma_f32_16x16x32_bf16(a1, b, acc[1][j], 0, 0, 0);
        }
    }

#pragma unroll
    for (int i = 0; i < 2; ++i)
#pragma unroll
        for (int j = 0; j < 4; ++j)
#pragma unroll
            for (int r = 0; r < 4; ++r) {
                int row = m0 + i * 16 + quad * 4 + r;
                if (row < N) {
                    int col = col0 + j * 16 + l15;
                    C[(size_t)row * ldC + col] = f2bf(acc[i][j][r]);
                }
            }
}

// ---------------- Aggregation (layers 0,1): wave/node, batched gathers ----------------
// C: N x 256 bf16; cols 0..127 = Wl path (gathered), 128..255 = Wr self path.

__global__ __launch_bounds__(256) void agg_relu_kernel(const unsigned short* __restrict__ C,
                                                       const int* __restrict__ row_ptr,
                                                       const int* __restrict__ adj,
                                                       const float* __restrict__ bias,
                                                       unsigned short* __restrict__ hout, int N) {
    int node = (int)((blockIdx.x * blockDim.x + threadIdx.x) >> 6);
    int lane = threadIdx.x & 63;
    if (node >= N) return;
    int beg = row_ptr[node], end = row_ptr[node + 1];
    float sx0 = 0.f, sy0 = 0.f, sx1 = 0.f, sy1 = 0.f;
    float sx2 = 0.f, sy2 = 0.f, sx3 = 0.f, sy3 = 0.f;

    int e = beg;
    while (e < end) {
        int cnt = end - e; if (cnt > 64) cnt = 64;
        int ll = lane; if (ll > cnt - 1) ll = cnt - 1;
        int myidx = adj[e + ll];                 // one coalesced load, clamped

        int i = 0;
        for (; i + 8 <= cnt; i += 8) {           // 8 gathers in flight
            int s0 = __shfl(myidx, i + 0), s1 = __shfl(myidx, i + 1);
            int s2 = __shfl(myidx, i + 2), s3 = __shfl(myidx, i + 3);
            int s4 = __shfl(myidx, i + 4), s5 = __shfl(myidx, i + 5);
            int s6 = __shfl(myidx, i + 6), s7 = __shfl(myidx, i + 7);
            unsigned int v0 = ((const unsigned int*)(C + (size_t)s0 * 256))[lane];
            unsigned int v1 = ((const unsigned int*)(C + (size_t)s1 * 256))[lane];
            unsigned int v2 = ((const unsigned int*)(C + (size_t)s2 * 256))[lane];
            unsigned int v3 = ((const unsigned int*)(C + (size_t)s3 * 256))[lane];
            unsigned int v4 = ((const unsigned int*)(C + (size_t)s4 * 256))[lane];
            unsigned int v5 = ((const unsigned int*)(C + (size_t)s5 * 256))[lane];
            unsigned int v6 = ((const unsigned int*)(C + (size_t)s6 * 256))[lane];
            unsigned int v7 = ((const unsigned int*)(C + (size_t)s7 * 256))[lane];
            sx0 += bf2f(v0 & 0xffffu); sy0 += bf2f(v0 >> 16);
            sx1 += bf2f(v1 & 0xffffu); sy1 += bf2f(v1 >> 16);
            sx2 += bf2f(v2 & 0xffffu); sy2 += bf2f(v2 >> 16);
            sx3 += bf2f(v3 & 0xffffu); sy3 += bf2f(v3 >> 16);
            sx0 += bf2f(v4 & 0xffffu); sy0 += bf2f(v4 >> 16);
            sx1 += bf2f(v5 & 0xffffu); sy1 += bf2f(v5 >> 16);
            sx2 += bf2f(v6 & 0xffffu); sy2 += bf2f(v6 >> 16);
            sx3 += bf2f(v7 & 0xffffu); sy3 += bf2f(v7 >> 16);
        }
        if (i < cnt) {                           // masked tail batch (clamped dup loads hit L1)
            int rem = cnt - i;
            int t0 = i, t1 = i + 1, t2 = i + 2, t3 = i + 3;
            int t4 = i + 4, t5 = i + 5, t6 = i + 6, t7 = i + 7;
            int c1 = cnt - 1;
            int s0 = __shfl(myidx, t0 > c1 ? c1 : t0), s1 = __shfl(myidx, t1 > c1 ? c1 : t1);
            int s2 = __shfl(myidx, t2 > c1 ? c1 : t2), s3 = __shfl(myidx, t3 > c1 ? c1 : t3);
            int s4 = __shfl(myidx, t4 > c1 ? c1 : t4), s5 = __shfl(myidx, t5 > c1 ? c1 : t5);
            int s6 = __shfl(myidx, t6 > c1 ? c1 : t6), s7 = __shfl(myidx, t7 > c1 ? c1 : t7);
            unsigned int v0 = ((const unsigned int*)(C + (size_t)s0 * 256))[lane];
            unsigned int v1 = ((const unsigned int*)(C + (size_t)s1 * 256))[lane];
            unsigned int v2 = ((const unsigned int*)(C + (size_t)s2 * 256))[lane];
            unsigned int v3 = ((const unsigned int*)(C + (size_t)s3 * 256))[lane];
            unsigned int v4 = ((const unsigned int*)(C + (size_t)s4 * 256))[lane];
            unsigned int v5 = ((const unsigned int*)(C + (size_t)s5 * 256))[lane];
            unsigned int v6 = ((const unsigned int*)(C + (size_t)s6 * 256))[lane];
            unsigned int v7 = ((const unsigned int*)(C + (size_t)s7 * 256))[lane];
            float m1 = rem > 1 ? 1.f : 0.f, m2 = rem > 2 ? 1.f : 0.f, m3 = rem > 3 ? 1.f : 0.f;
            float m4 = rem > 4 ? 1.f : 0.f, m5 = rem > 5 ? 1.f : 0.f, m6 = rem > 6 ? 1.f : 0.f;
            float m7 = rem > 7 ? 1.f : 0.f;
            sx0 += bf2f(v0 & 0xffffu);      sy0 += bf2f(v0 >> 16);
            sx1 += m1 * bf2f(v1 & 0xffffu); sy1 += m1 * bf2f(v1 >> 16);
            sx2 += m2 * bf2f(v2 & 0xffffu); sy2 += m2 * bf2f(v2 >> 16);
            sx3 += m3 * bf2f(v3 & 0xffffu); sy3 += m3 * bf2f(v3 >> 16);
            sx0 += m4 * bf2f(v4 & 0xffffu); sy0 += m4 * bf2f(v4 >> 16);
            sx1 += m5 * bf2f(v5 & 0xffffu); sy1 += m5 * bf2f(v5 >> 16);
            sx2 += m6 * bf2f(v6 & 0xffffu); sy2 += m6 * bf2f(v6 >> 16);
            sx3 += m7 * bf2f(v7 & 0xffffu); sy3 += m7 * bf2f(v7 >> 16);
        }
        e += cnt;
    }

    float sx = (sx0 + sx1) + (sx2 + sx3);
    float sy = (sy0 + sy1) + (sy2 + sy3);
    int deg = end - beg;
    float inv = 1.0f / (float)(deg > 1 ? deg : 1);
    float2 bb = ((const float2*)bias)[lane];
    unsigned int rv = ((const unsigned int*)(C + (size_t)node * 256))[64 + lane];
    float ox = fmaxf(sx * inv + bb.x + bf2f(rv & 0xffffu), 0.f);
    float oy = fmaxf(sy * inv + bb.y + bf2f(rv >> 16), 0.f);
    unsigned int p = (unsigned int)f2bf(ox) | ((unsigned int)f2bf(oy) << 16);
    ((unsigned int*)(hout + (size_t)node * 128))[lane] = p;
}

// ---------------- Final layer: bf16 C (N x 128), batched gathers, fused log_softmax ----------------

__global__ __launch_bounds__(256) void final_kernel(const unsigned short* __restrict__ C,
                                                    const int* __restrict__ row_ptr,
                                                    const int* __restrict__ adj,
                                                    const float* __restrict__ bias,
                                                    float* __restrict__ out, int N) {
    int node = (int)((blockIdx.x * blockDim.x + threadIdx.x) >> 6);
    int lane = threadIdx.x & 63;
    if (node >= N) return;
    int beg = row_ptr[node], end = row_ptr[node + 1];
    float a0 = 0.f, a1 = 0.f, a2 = 0.f, a3 = 0.f;

    int e = beg;
    while (e < end) {
        int cnt = end - e; if (cnt > 64) cnt = 64;
        int ll = lane; if (ll > cnt - 1) ll = cnt - 1;
        int myidx = adj[e + ll];

        int i = 0;
        for (; i + 8 <= cnt; i += 8) {
            int s0 = __shfl(myidx, i + 0), s1 = __shfl(myidx, i + 1);
            int s2 = __shfl(myidx, i + 2), s3 = __shfl(myidx, i + 3);
            int s4 = __shfl(myidx, i + 4), s5 = __shfl(myidx, i + 5);
            int s6 = __shfl(myidx, i + 6), s7 = __shfl(myidx, i + 7);
            float v0 = bf2f((unsigned int)C[(size_t)s0 * 128 + lane]);
            float v1 = bf2f((unsigned int)C[(size_t)s1 * 128 + lane]);
            float v2 = bf2f((unsigned int)C[(size_t)s2 * 128 + lane]);
            float v3 = bf2f((unsigned int)C[(size_t)s3 * 128 + lane]);
            float v4 = bf2f((unsigned int)C[(size_t)s4 * 128 + lane]);
            float v5 = bf2f((unsigned int)C[(size_t)s5 * 128 + lane]);
            float v6 = bf2f((unsigned int)C[(size_t)s6 * 128 + lane]);
            float v7 = bf2f((unsigned int)C[(size_t)s7 * 128 + lane]);
            a0 += v0 + v4; a1 += v1 + v5; a2 += v2 + v6; a3 += v3 + v7;
        }
        if (i < cnt) {
            int rem = cnt - i, c1 = cnt - 1;
            int t;
            t = i + 0; int s0 = __shfl(myidx, t > c1 ? c1 : t);
            t = i + 1; int s1 = __shfl(myidx, t > c1 ? c1 : t);
            t = i + 2; int s2 = __shfl(myidx, t > c1 ? c1 : t);
            t = i + 3; int s3 = __shfl(myidx, t > c1 ? c1 : t);
            t = i + 4; int s4 = __shfl(myidx, t > c1 ? c1 : t);
            t = i + 5; int s5 = __shfl(myidx, t > c1 ? c1 : t);
            t = i + 6; int s6 = __shfl(myidx, t > c1 ? c1 : t);
            t = i + 7; int s7 = __shfl(myidx, t > c1 ? c1 : t);
            float v0 = bf2f((unsigned int)C[(size_t)s0 * 128 + lane]);
            float v1 = bf2f((unsigned int)C[(size_t)s1 * 128 + lane]);
            float v2 = bf2f((unsigned int)C[(size_t)s2 * 128 + lane]);
            float v3 = bf2f((unsigned int)C[(size_t)s3 * 128 + lane]);
            float v4 = bf2f((unsigned int)C[(size_t)s4 * 128 + lane]);
            float v5 = bf2f((unsigned int)C[(size_t)s5 * 128 + lane]);
            float v6 = bf2f((unsigned int)C[(size_t)s6 * 128 + lane]);
            float v7 = bf2f((unsigned int)C[(size_t)s7 * 128 + lane]);
            float m1 = rem > 1 ? 1.f : 0.f, m2 = rem > 2 ? 1.f : 0.f, m3 = rem > 3 ? 1.f : 0.f;
            float m4 = rem > 4 ? 1.f : 0.f, m5 = rem > 5 ? 1.f : 0.f, m6 = rem > 6 ? 1.f : 0.f;
            float m7 = rem > 7 ? 1.f : 0.f;
            a0 += v0 + m4 * v4; a1 += m1 * v1 + m5 * v5;
            a2 += m2 * v2 + m6 * v6; a3 += m3 * v3 + m7 * v7;
        }
        e += cnt;
    }

    float sum = (a0 + a1) + (a2 + a3);
    int deg = end - beg;
    float inv = 1.0f / (float)(deg > 1 ? deg : 1);
    float u = sum * inv + bias[lane] + bf2f((unsigned int)C[(size_t)node * 128 + 64 + lane]);

    float m = u;
#pragma unroll
    for (int off = 32; off > 0; off >>= 1) m = fmaxf(m, __shfl_xor(m, off));
    float ex = __expf(u - m);
    float se = ex;
#pragma unroll
    for (int off = 32; off > 0; off >>= 1) se += __shfl_xor(se, off);
    out[(size_t)node * 64 + lane] = (u - m) - __logf(se);
}

// ---------------- Launch ----------------

extern "C" void kernel_launch(void* const* d_in, const int* in_sizes, int n_in,
                              void* d_out, int out_size, void* d_ws, size_t ws_size,
                              hipStream_t stream) {
    const float* x   = (const float*)d_in[0];
    const int*   ei  = (const int*)d_in[1];
    const float* Wl0 = (const float*)d_in[2];
    const float* bl0 = (const float*)d_in[3];
    const float* Wr0 = (const float*)d_in[4];
    const float* Wl1 = (const float*)d_in[5];
    const float* bl1 = (const float*)d_in[6];
    const float* Wr1 = (const float*)d_in[7];
    const float* Wl2 = (const float*)d_in[8];
    const float* bl2 = (const float*)d_in[9];
    const float* Wr2 = (const float*)d_in[10];
    float* out = (float*)d_out;

    const int N = in_sizes[0] / 128;   // 50000
    const int E = in_sizes[1] / 2;     // 800000
    const int G = (N + 255) / 256;     // scan blocks (196 <= 256)

    char* ws = (char*)d_ws;
    auto alloc = [&](size_t bytes) {
        char* p = ws;
        ws += (bytes + 255) & ~(size_t)255;
        return p;
    };
    int*   deg       = (int*)alloc((size_t)N * 4);
    int*   row_ptr   = (int*)alloc((size_t)(N + 1) * 4);
    int*   cursor    = (int*)alloc((size_t)N * 4);
    int*   adj       = (int*)alloc((size_t)E * 4);
    int*   blockSums = (int*)alloc((size_t)G * 4);
    int*   blockOff  = (int*)alloc((size_t)G * 4);
    unsigned short* xbf = (unsigned short*)alloc((size_t)N * 128 * 2);
    unsigned short* wbf = (unsigned short*)alloc((size_t)81920 * 2);
    unsigned short* C   = (unsigned short*)alloc((size_t)N * 256 * 2);
    unsigned short* hA  = (unsigned short*)alloc((size_t)N * 128 * 2);
    unsigned short* hB  = (unsigned short*)alloc((size_t)N * 128 * 2);

    const int* dstp = ei;       // edge_index row 0 = dst
    const int* srcp = ei + E;   // edge_index row 1 = src

    // CSR build
    hipMemsetAsync(deg, 0, (size_t)N * 4, stream);
    hist_kernel<<<(E + 255) / 256, 256, 0, stream>>>(dstp, deg, E);
    partial_kernel<<<G, 256, 0, stream>>>(deg, blockSums, N);
    offsets_kernel<<<1, 256, 0, stream>>>(blockSums, blockOff, G, row_ptr + N);
    scatter_kernel<<<G, 256, 0, stream>>>(deg, blockOff, row_ptr, cursor, N);
    fill_kernel<<<(E + 255) / 256, 256, 0, stream>>>(dstp, srcp, cursor, adj, E);

    // casts
    cast_x_kernel<<<(N * 64 + 255) / 256, 256, 0, stream>>>(x, xbf, N * 64);
    cast_w_kernel<<<dim3(32, 6), 256, 0, stream>>>(Wl0, Wr0, Wl1, Wr1, Wl2, Wr2, wbf);
    unsigned short* wl0 = wbf;
    unsigned short* wr0 = wbf + 16384;
    unsigned short* wl1 = wbf + 32768;
    unsigned short* wr1 = wbf + 49152;
    unsigned short* wl2 = wbf + 65536;
    unsigned short* wr2 = wbf + 73728;

    dim3 blk(256);
    int gemmRows = (N + 127) / 128;
    int aggBlocks = (N * 64 + 255) / 256;

    // Layer 0
    gemm_mfma_kernel<<<dim3(gemmRows, 4), blk, 0, stream>>>(xbf, wl0, wr0, C, N, 256);
    agg_relu_kernel<<<aggBlocks, blk, 0, stream>>>(C, row_ptr, adj, bl0, hA, N);
    // Layer 1
    gemm_mfma_kernel<<<dim3(gemmRows, 4), blk, 0, stream>>>(hA, wl1, wr1, C, N, 256);
    agg_relu_kernel<<<aggBlocks, blk, 0, stream>>>(C, row_ptr, adj, bl1, hB, N);
    // Layer 2 + log_softmax
    gemm_mfma_kernel<<<dim3(gemmRows, 2), blk, 0, stream>>>(hB, wl2, wr2, C, N, 128);
    final_kernel<<<aggBlocks, blk, 0, stream>>>(C, row_ptr, adj, bl2, out, N);
}